// Round 9
// baseline (248.557 us; speedup 1.0000x reference)
//
#include <hip/hip_runtime.h>

// entmax-1.5 attention, round 15: CLEAN barrier-free test. r8's direct
// global->register fragment structure was never run unconfounded (r8 =
// 32-reg cap spills; r10 = f32 K loads + in-loop cvt). Now with all
// verified deltas: bf16 Kb/Vt (r13), XCD swizzle -> K/V L2-hot (r14:
// FETCH 17 MB), bit-packed mask (r14), (512,3) -> ~85-reg cap no spill,
// cand overlay on sc row (r11/r12 verified). Wave w reads only K/V rows
// w*16..w*16+15 -> no cross-wave staging -> phases 1 & 3 barrier-free;
// EXACTLY 2 __syncthreads in the kernel. LDS = sc only = 32,768 B.
// 3 blocks/CU (24 waves) self-paced; depth-1 fragment prefetch is
// TLP-covered (all K/V reads are XCD-L2 hits).
// Tripwire: WRITE_SIZE > 16.4 MB = spills -> relax to (512,2).

#define S_ 1024
#define D_ 128
#define NEG_INF_F (-1.0e12f)
#define SCALE_F 0.08838834764831845f  // 1/sqrt(128)
#define NITER 14                      // dTau=6e-5 -> out err ~1e-3 << 0.0766
#define CCAP 512                      // cand cap (sc row = 512 f32)

typedef float f32x4 __attribute__((ext_vector_type(4)));
typedef short short8 __attribute__((ext_vector_type(8)));

__device__ __forceinline__ ushort f2bf(float x) {   // RNE f32 -> bf16
    unsigned u = __builtin_bit_cast(unsigned, x);
    u += 0x7FFFu + ((u >> 16) & 1u);
    return (ushort)(u >> 16);
}
__device__ __forceinline__ float bf2f(ushort h) {
    unsigned u = ((unsigned)h) << 16;
    return __builtin_bit_cast(float, u);
}
__device__ __forceinline__ short8 cvt8(float4 a, float4 b) {
    short8 r; ushort* p = (ushort*)&r;
    p[0] = f2bf(a.x); p[1] = f2bf(a.y); p[2] = f2bf(a.z); p[3] = f2bf(a.w);
    p[4] = f2bf(b.x); p[5] = f2bf(b.y); p[6] = f2bf(b.z); p[7] = f2bf(b.w);
    return r;
}

// ---- fused pre-kernel ---------------------------------------------------
// blocks 0..4095: K->bf16. 4096..5119: V->bf16-T. 5120..5631: mask pack.
__global__ __launch_bounds__(256)
void pre_cvt(const float* __restrict__ K, const float* __restrict__ V,
             const int* __restrict__ M,
             ushort* __restrict__ Kb, ushort* __restrict__ Vt,
             unsigned* __restrict__ Mp)
{
    __shared__ __align__(16) ushort tileT[64][68];  // [d][key], pad->8B rows
    const int t = threadIdx.x;
    if (blockIdx.x < 4096) {                        // K convert (coalesced)
        int i = blockIdx.x * 256 + t;               // 1,048,576 float4s
        float4 v = ((const float4*)K)[i];
        ushort4 o;
        o.x = f2bf(v.x); o.y = f2bf(v.y); o.z = f2bf(v.z); o.w = f2bf(v.w);
        ((ushort4*)Kb)[i] = o;
        return;
    }
    if (blockIdx.x >= 5120) {                       // mask pack (1 bit/key)
        const int g = (blockIdx.x - 5120) * 256 + t;    // 0..131071
        const int mrow = g >> 5, u = g & 31;            // row 0..4095
        const int* src = M + (size_t)mrow * 1024 + u * 8;
        unsigned out = 0;
        #pragma unroll
        for (int c = 0; c < 4; ++c) {               // byte c: keys c*256+u*8..+7
            int4 a = *(const int4*)(src + c * 256);
            int4 b4 = *(const int4*)(src + c * 256 + 4);
            unsigned byte =
                (unsigned)(a.x != 0)       | ((unsigned)(a.y != 0) << 1) |
                ((unsigned)(a.z != 0) << 2)| ((unsigned)(a.w != 0) << 3) |
                ((unsigned)(b4.x != 0) << 4)| ((unsigned)(b4.y != 0) << 5) |
                ((unsigned)(b4.z != 0) << 6)| ((unsigned)(b4.w != 0) << 7);
            out |= byte << (c * 8);
        }
        Mp[(size_t)mrow * 32 + u] = out;
        return;
    }
    // V transpose: 64x64 tile per block. 1024 blocks = 32 bh x 16 kt x 2 dh
    const int vb = blockIdx.x - 4096;
    const int bh = vb >> 5, r5 = vb & 31, kt = r5 >> 1, dh = r5 & 1;
    const float* src = V + ((size_t)(bh * S_ + kt * 64)) * D_ + dh * 64;
    #pragma unroll
    for (int i = 0; i < 4; ++i) {                   // 1024 float4 loads
        int idx = t + i * 256, r = idx >> 4, c = idx & 15;
        float4 vv = *(const float4*)(src + (size_t)r * D_ + c * 4);
        tileT[c * 4 + 0][r] = f2bf(vv.x);           // scatter-transpose
        tileT[c * 4 + 1][r] = f2bf(vv.y);
        tileT[c * 4 + 2][r] = f2bf(vv.z);
        tileT[c * 4 + 3][r] = f2bf(vv.w);
    }
    __syncthreads();
    ushort* dst = Vt + ((size_t)(bh * D_ + dh * 64)) * S_ + kt * 64;
    #pragma unroll
    for (int i = 0; i < 2; ++i) {                   // contiguous reads/stores
        int idx = t + i * 256, d = idx >> 3, jj = idx & 7;
        short8 val = *(const short8*)&tileT[d][jj * 8];
        *(short8*)(dst + (size_t)d * S_ + jj * 8) = val;
    }
}

// ---- main kernel --------------------------------------------------------
__global__ __launch_bounds__(512, 3)
void entmax_attn(const float* __restrict__ Q, const ushort* __restrict__ Kb,
                 const ushort* __restrict__ Vt, const unsigned* __restrict__ Mp,
                 float* __restrict__ O)
{
    __shared__ __align__(16) ushort sc[16][1024];   // scores/P/cand, swizzled

    const int t = threadIdx.x;
    const int w = t >> 6, lane = t & 63, l = lane & 15, quad = lane >> 4;
    // XCD swizzle (bijective, 2048%8==0): XCD j gets 4 whole bh.
    const int swz = (blockIdx.x & 7) * 256 + (blockIdx.x >> 3);
    const int bh = swz >> 6, qt = swz & 63, b = bh >> 3;

    const ushort* kb_bh = Kb + (size_t)bh * (S_ * D_);
    const ushort* vt_bh = Vt + (size_t)bh * (D_ * S_);

    // packed mask word: ONE dword/thread, latency hides under phase 1
    const int row = t >> 5, u = t & 31;
    const int qg = qt * 16 + row;
    const unsigned mw = Mp[(size_t)(b * S_ + qg) * 32 + u];

    // ---- Q fragments direct from global f32 (8 KB/block, L1/L2) --------
    short8 aq[4];                                   // A[m=l][k=ks*32+quad*8+e]
    {
        const float* qr = Q + ((size_t)(bh * S_ + qt * 16 + l)) * D_ + quad * 8;
        #pragma unroll
        for (int ks = 0; ks < 4; ++ks) {
            float4 qa = *(const float4*)(qr + ks * 32);
            float4 qb = *(const float4*)(qr + ks * 32 + 4);
            aq[ks] = cvt8(qa, qb);
        }
    }

    // K fragment base: key row = w*16+l, chunk = quad*8 (16B per fragment)
    const ushort* kp = kb_bh + (size_t)(w * 16 + l) * D_ + quad * 8;
    short8 c0 = *(const short8*)(kp +  0);          // tile 0
    short8 c1 = *(const short8*)(kp + 32);
    short8 c2 = *(const short8*)(kp + 64);
    short8 c3 = *(const short8*)(kp + 96);

    // ---- phase 1: QK^T, 8 key-tiles, barrier-free ----------------------
    #pragma unroll 1
    for (int kt = 0; kt < 7; ++kt) {
        const ushort* np = kp + (size_t)(kt + 1) * (128 * D_);
        short8 n0 = *(const short8*)(np +  0);      // prefetch next tile
        short8 n1 = *(const short8*)(np + 32);
        short8 n2 = *(const short8*)(np + 64);
        short8 n3 = *(const short8*)(np + 96);
        f32x4 acc = {0.f, 0.f, 0.f, 0.f};
        __builtin_amdgcn_s_setprio(1);
        acc = __builtin_amdgcn_mfma_f32_16x16x32_bf16(aq[0], c0, acc, 0, 0, 0);
        acc = __builtin_amdgcn_mfma_f32_16x16x32_bf16(aq[1], c1, acc, 0, 0, 0);
        acc = __builtin_amdgcn_mfma_f32_16x16x32_bf16(aq[2], c2, acc, 0, 0, 0);
        acc = __builtin_amdgcn_mfma_f32_16x16x32_bf16(aq[3], c3, acc, 0, 0, 0);
        __builtin_amdgcn_s_setprio(0);
        const int coln = kt * 16 + w * 2 + (l >> 3);    // col>>3
        #pragma unroll
        for (int r = 0; r < 4; ++r) {
            const int rr = quad * 4 + r;
            sc[rr][((coln ^ (rr & 7)) << 3) + (l & 7)] = f2bf(acc[r] * SCALE_F);
        }
        c0 = n0; c1 = n1; c2 = n2; c3 = n3;
    }
    {   // kt = 7 (peeled; no prefetch)
        f32x4 acc = {0.f, 0.f, 0.f, 0.f};
        __builtin_amdgcn_s_setprio(1);
        acc = __builtin_amdgcn_mfma_f32_16x16x32_bf16(aq[0], c0, acc, 0, 0, 0);
        acc = __builtin_amdgcn_mfma_f32_16x16x32_bf16(aq[1], c1, acc, 0, 0, 0);
        acc = __builtin_amdgcn_mfma_f32_16x16x32_bf16(aq[2], c2, acc, 0, 0, 0);
        acc = __builtin_amdgcn_mfma_f32_16x16x32_bf16(aq[3], c3, acc, 0, 0, 0);
        __builtin_amdgcn_s_setprio(0);
        const int coln = 7 * 16 + w * 2 + (l >> 3);
        #pragma unroll
        for (int r = 0; r < 4; ++r) {
            const int rr = quad * 4 + r;
            sc[rr][((coln ^ (rr & 7)) << 3) + (l & 7)] = f2bf(acc[r] * SCALE_F);
        }
    }
    // V^T tile-0 fragment loads: issue now, ready long before phase 3
    const ushort* vp = vt_bh + (size_t)(w * 16 + l) * S_ + quad * 8;
    c0 = *(const short8*)(vp +  0);
    c1 = *(const short8*)(vp + 32);
    c2 = *(const short8*)(vp + 64);
    c3 = *(const short8*)(vp + 96);
    __syncthreads();                                // all scores visible

    // ---- phase 2: regather + mask(packed) + max + normalize ------------
    float x[32];
    #pragma unroll
    for (int c = 0; c < 4; ++c) {
        short8 v8 = *(const short8*)&sc[row][((c * 32 + u) ^ (row & 7)) << 3];
        #pragma unroll
        for (int e = 0; e < 8; ++e) x[c * 8 + e] = bf2f(((ushort*)&v8)[e]);
    }
    #pragma unroll
    for (int c = 0; c < 4; ++c) {                   // bit j of byte c
        #pragma unroll
        for (int e = 0; e < 8; ++e)
            if (!((mw >> (c * 8 + e)) & 1u)) x[c * 8 + e] = NEG_INF_F;
    }
    float mx = -3.0e38f;
    #pragma unroll
    for (int j = 0; j < 32; ++j) mx = fmaxf(mx, x[j]);
    #pragma unroll
    for (int off = 1; off < 32; off <<= 1) mx = fmaxf(mx, __shfl_xor(mx, off));
    #pragma unroll
    for (int j = 0; j < 32; ++j) x[j] = (x[j] - mx) * 0.5f;   // x <= 0

    // ---- candidate compaction into own sc row (scores dead; lockstep) --
    float* cand = (float*)&sc[row][0];              // 512 f32 = the row
    const unsigned long long halfmask =
        (lane >= 32) ? 0xFFFFFFFF00000000ull : 0x00000000FFFFFFFFull;
    int cnt = 0;
    #pragma unroll
    for (int j = 0; j < 32; ++j) {
        const bool p = (x[j] > -1.0f);              // tau* >= -1
        unsigned long long bal = __ballot(p) & halfmask;
        if (p) {
            int pos = cnt + (int)__builtin_amdgcn_mbcnt_hi(
                (unsigned)(bal >> 32),
                __builtin_amdgcn_mbcnt_lo((unsigned)bal, 0));
            if (pos < CCAP) cand[pos] = x[j];
        }
        cnt += __popcll(bal);
    }

    // ---- tau bisection on f(tau)=sum max(0,x-tau)^2=1, root in [-1,0] --
    float tau;
    if (cnt <= CCAP) {                              // compact path (normal)
        float lo = -1.f, hi = 0.f;
        #pragma unroll 1
        for (int it = 0; it < NITER; ++it) {
            const float tm = 0.5f * (lo + hi);
            float f = 0.f;
            for (int j = u; j < cnt; j += 32) {
                float d = fmaxf(cand[j] - tm, 0.f);
                f = fmaf(d, d, f);
            }
            #pragma unroll
            for (int off = 1; off < 32; off <<= 1) f += __shfl_xor(f, off);
            const bool ge = (f >= 1.f);
            lo = ge ? tm : lo;
            hi = ge ? hi : tm;
        }
        tau = 0.5f * (lo + hi);
    } else {                                        // fallback: full solve
        float lo = -1.f, hi = 0.f;
        #pragma unroll 1
        for (int it = 0; it < NITER; ++it) {
            const float tm = 0.5f * (lo + hi);
            float f = 0.f;
            #pragma unroll
            for (int j = 0; j < 32; ++j) {
                float d = fmaxf(x[j] - tm, 0.f);
                f = fmaf(d, d, f);
            }
            #pragma unroll
            for (int off = 1; off < 32; off <<= 1) f += __shfl_xor(f, off);
            const bool ge = (f >= 1.f);
            lo = ge ? tm : lo;
            hi = ge ? hi : tm;
        }
        tau = 0.5f * (lo + hi);
    }

    // ---- y = max(0,x-tau)^2 back into sc (dense, swizzled) -------------
    #pragma unroll
    for (int c = 0; c < 4; ++c) {
        short8 v8;
        #pragma unroll
        for (int e = 0; e < 8; ++e) {
            float d = fmaxf(x[c * 8 + e] - tau, 0.f);
            ((ushort*)&v8)[e] = f2bf(d * d);
        }
        *(short8*)&sc[row][((c * 32 + u) ^ (row & 7)) << 3] = v8;
    }
    __syncthreads();                                // all y visible

    // ---- phase 3: O = P @ V^T, 8 key-tiles, barrier-free ---------------
    f32x4 oa = {0.f, 0.f, 0.f, 0.f};
    #pragma unroll 1
    for (int vt = 0; vt < 7; ++vt) {
        const ushort* np = vp + (size_t)(vt + 1) * 128;
        short8 n0 = *(const short8*)(np +  0);      // prefetch next tile
        short8 n1 = *(const short8*)(np + 32);
        short8 n2 = *(const short8*)(np + 64);
        short8 n3 = *(const short8*)(np + 96);
        short8 a0 = *(const short8*)&sc[l][((vt * 16 +  0 + quad) ^ (l & 7)) << 3];
        short8 a1 = *(const short8*)&sc[l][((vt * 16 +  4 + quad) ^ (l & 7)) << 3];
        __builtin_amdgcn_s_setprio(1);
        oa = __builtin_amdgcn_mfma_f32_16x16x32_bf16(a0, c0, oa, 0, 0, 0);
        oa = __builtin_amdgcn_mfma_f32_16x16x32_bf16(a1, c1, oa, 0, 0, 0);
        __builtin_amdgcn_s_setprio(0);
        short8 a2 = *(const short8*)&sc[l][((vt * 16 +  8 + quad) ^ (l & 7)) << 3];
        short8 a3 = *(const short8*)&sc[l][((vt * 16 + 12 + quad) ^ (l & 7)) << 3];
        __builtin_amdgcn_s_setprio(1);
        oa = __builtin_amdgcn_mfma_f32_16x16x32_bf16(a2, c2, oa, 0, 0, 0);
        oa = __builtin_amdgcn_mfma_f32_16x16x32_bf16(a3, c3, oa, 0, 0, 0);
        __builtin_amdgcn_s_setprio(0);
        c0 = n0; c1 = n1; c2 = n2; c3 = n3;
    }
    {   // vt = 7 (peeled)
        short8 a0 = *(const short8*)&sc[l][((7 * 16 +  0 + quad) ^ (l & 7)) << 3];
        short8 a1 = *(const short8*)&sc[l][((7 * 16 +  4 + quad) ^ (l & 7)) << 3];
        short8 a2 = *(const short8*)&sc[l][((7 * 16 +  8 + quad) ^ (l & 7)) << 3];
        short8 a3 = *(const short8*)&sc[l][((7 * 16 + 12 + quad) ^ (l & 7)) << 3];
        __builtin_amdgcn_s_setprio(1);
        oa = __builtin_amdgcn_mfma_f32_16x16x32_bf16(a0, c0, oa, 0, 0, 0);
        oa = __builtin_amdgcn_mfma_f32_16x16x32_bf16(a1, c1, oa, 0, 0, 0);
        oa = __builtin_amdgcn_mfma_f32_16x16x32_bf16(a2, c2, oa, 0, 0, 0);
        oa = __builtin_amdgcn_mfma_f32_16x16x32_bf16(a3, c3, oa, 0, 0, 0);
        __builtin_amdgcn_s_setprio(0);
    }

    // ---- epilogue: C/D map (col=d-within-slice=l, row=q=quad*4+r) ------
    float* ob = O + ((size_t)bh * S_ + (size_t)qt * 16) * D_;
    #pragma unroll
    for (int r = 0; r < 4; ++r)
        ob[(size_t)(quad * 4 + r) * D_ + w * 16 + l] = oa[r];
}

extern "C" void kernel_launch(void* const* d_in, const int* in_sizes, int n_in,
                              void* d_out, int out_size, void* d_ws, size_t ws_size,
                              hipStream_t stream) {
    const float* q = (const float*)d_in[0];
    const float* k = (const float*)d_in[1];
    const float* v = (const float*)d_in[2];
    const int*   m = (const int*)d_in[3];
    float*       o = (float*)d_out;

    ushort*   Kb = (ushort*)d_ws;                         // 8,388,608 B
    ushort*   Vt = (ushort*)((char*)d_ws + 8388608);      // 8,388,608 B
    unsigned* Mp = (unsigned*)((char*)d_ws + 16777216);   //   524,288 B

    pre_cvt<<<5632, 256, 0, stream>>>(k, v, m, Kb, Vt, Mp);
    entmax_attn<<<2048, 512, 0, stream>>>(q, Kb, Vt, Mp, o);
}